// Round 1
// baseline (757.467 us; speedup 1.0000x reference)
//
#include <hip/hip_runtime.h>

// B=2048, N=256, M=128 ; out[b] = W^T X[b] W  (einsum "ji,bjk,kl->bil")
// v3: streaming restructure. Stage1 A-fragments (X) are loaded DIRECTLY from
// global (8 contiguous f32/lane), each X element read exactly once per block;
// no X LDS staging, no per-iteration barrier. Wave w computes U p-tiles
// {2w,2w+1} (U = X W, all 4 col-tiles, A-frag reused x4), transforms D->B
// layout in-register (v2-verified shfl trick) and deposits U in LDS in
// B-fragment-linear order (conflict-free b128). ONE barrier. Stage2: wave w
// owns out row-block w: 16 kt x (1 Wf A-frag from L2 + 4 U B-frags from LDS
// + 4 MFMA). Deep grouped X prefetch keeps ~8KB/wave posted to HBM
// continuously -> BW-bound operation.

typedef __attribute__((ext_vector_type(8))) short short8;
typedef __attribute__((ext_vector_type(16))) float floatx16;

struct __align__(16) u4 { unsigned int x, y, z, w; };

__device__ __forceinline__ unsigned short f2bf(float f) {
  unsigned int u = __builtin_bit_cast(unsigned int, f);
  u += 0x7FFFu + ((u >> 16) & 1u);          // RNE
  return (unsigned short)(u >> 16);
}

// pack two f32 -> one dword of 2 bf16 (RNE), via v_perm_b32
__device__ __forceinline__ unsigned bfpack(float x, float y) {
  unsigned ux = __builtin_bit_cast(unsigned, x);
  unsigned uy = __builtin_bit_cast(unsigned, y);
  ux += 0x7FFFu + ((ux >> 16) & 1u);
  uy += 0x7FFFu + ((uy >> 16) & 1u);
  return __builtin_amdgcn_perm(uy, ux, 0x07060302u);  // [uy.hi16 | ux.hi16]
}

// ---------------------------------------------------------------------------
// prep: W (256x128 f32 row-major) -> fragment-ordered bf16 in ws.
// Wf[(((blk*16)+t)*64 + l)*8 + j] = W[16t + 8*(l>>5) + j][32*blk + (l&31)]
// Serves stage1 B-operand (blk = U col-tile) AND stage2 A-operand
// (blk = out row-block) — identical lane layout for A and B operands.
// ---------------------------------------------------------------------------
__global__ void prep_w(const float* __restrict__ W, unsigned short* __restrict__ Wf) {
  int g = blockIdx.x * 256 + threadIdx.x;   // 4096 fragments of 8 elems
  int l = g & 63;
  int t = (g >> 6) & 15;
  int blk = g >> 10;
  int row0 = 16 * t + ((l >> 5) << 3);
  int col  = 32 * blk + (l & 31);
  unsigned short tmp[8];
#pragma unroll
  for (int j = 0; j < 8; ++j) tmp[j] = f2bf(W[(row0 + j) * 128 + col]);
  u4 v;
  v.x = (unsigned)tmp[0] | ((unsigned)tmp[1] << 16);
  v.y = (unsigned)tmp[2] | ((unsigned)tmp[3] << 16);
  v.z = (unsigned)tmp[4] | ((unsigned)tmp[5] << 16);
  v.w = (unsigned)tmp[6] | ((unsigned)tmp[7] << 16);
  *(u4*)(Wf + (size_t)g * 8) = v;
}

// ---------------------------------------------------------------------------
// main kernel: one batch per block, 256 threads (4 waves), ONE barrier.
// ---------------------------------------------------------------------------
__global__ __launch_bounds__(256, 2) void spd_kernel(
    const float* __restrict__ X,
    const unsigned short* __restrict__ Wf,
    float* __restrict__ out)
{
  // U exchange buffer, B-fragment-linear: frag (kt,ct) at [((kt*4+ct)*64+lane)*8]
  __shared__ __align__(16) unsigned short Us[64 * 64 * 8];   // 64 KB

  const int b    = blockIdx.x;
  const int tid  = threadIdx.x;
  const int wave = tid >> 6;
  const int lane = tid & 63;
  const int l31  = lane & 31;
  const int hi   = lane >> 5;   // 0/1

  const float* xb = X + (size_t)b * 65536;

  // ================= stage 1: U = X @ W, two p-tiles per wave =================
#pragma unroll
  for (int s = 0; s < 2; ++s) {
    const int p = 2 * wave + s;
    // lane's A-fragment row base: row = 32p + l31, col base 8*hi
    const float* xr = xb + (size_t)(32 * p + l31) * 256 + 8 * hi;

    floatx16 acc[4];
#pragma unroll
    for (int ct = 0; ct < 4; ++ct)
#pragma unroll
      for (int i = 0; i < 16; ++i) acc[ct][i] = 0.0f;

    // X prefetch: groups of 4 kt, ping-pong (one full group = 4 KB/wave posted)
    float4 xa[2][4][2];
#pragma unroll
    for (int k = 0; k < 4; ++k) {
      xa[0][k][0] = *(const float4*)(xr + 16 * k);
      xa[0][k][1] = *(const float4*)(xr + 16 * k + 4);
    }
    // Wf B-fragment prefetch (L2), distance 1 kt
    short8 wcur[4], wnxt[4];
#pragma unroll
    for (int ct = 0; ct < 4; ++ct)
      wcur[ct] = *(const short8*)(Wf + (size_t)((ct * 16 + 0) * 64 + lane) * 8);

#pragma unroll
    for (int g = 0; g < 4; ++g) {
      if (g < 3) {                       // issue next group's X loads early
#pragma unroll
        for (int k = 0; k < 4; ++k) {
          xa[(g + 1) & 1][k][0] = *(const float4*)(xr + 16 * (4 * (g + 1) + k));
          xa[(g + 1) & 1][k][1] = *(const float4*)(xr + 16 * (4 * (g + 1) + k) + 4);
        }
      }
#pragma unroll
      for (int k = 0; k < 4; ++k) {
        const int kt = 4 * g + k;
        if (kt < 15) {                   // Wf prefetch for kt+1
#pragma unroll
          for (int ct = 0; ct < 4; ++ct)
            wnxt[ct] = *(const short8*)(Wf + (size_t)((ct * 16 + kt + 1) * 64 + lane) * 8);
        }
        float4 va = xa[g & 1][k][0], vb = xa[g & 1][k][1];
        u4 av;
        av.x = bfpack(va.x, va.y);
        av.y = bfpack(va.z, va.w);
        av.z = bfpack(vb.x, vb.y);
        av.w = bfpack(vb.z, vb.w);
        short8 afr = __builtin_bit_cast(short8, av);
#pragma unroll
        for (int ct = 0; ct < 4; ++ct)
          acc[ct] = __builtin_amdgcn_mfma_f32_32x32x16_bf16(afr, wcur[ct], acc[ct], 0, 0, 0);
        if (kt < 15) {
#pragma unroll
          for (int ct = 0; ct < 4; ++ct) wcur[ct] = wnxt[ct];
        }
      }
    }

    // ---- D-layout -> B-operand layout, in-register (v2-verified), -> LDS ----
#pragma unroll
    for (int ct = 0; ct < 4; ++ct) {
      unsigned d[8];
#pragma unroll
      for (int i = 0; i < 8; ++i) d[i] = bfpack(acc[ct][2 * i], acc[ct][2 * i + 1]);
      unsigned e0 = __shfl_xor(hi ? d[0] : d[2], 32, 64);
      unsigned e1 = __shfl_xor(hi ? d[1] : d[3], 32, 64);
      unsigned e2 = __shfl_xor(hi ? d[4] : d[6], 32, 64);
      unsigned e3 = __shfl_xor(hi ? d[5] : d[7], 32, 64);
      u4 b0v, b1v;
      b0v.x = hi ? e0   : d[0];  b0v.y = hi ? e1   : d[1];
      b0v.z = hi ? d[2] : e0;    b0v.w = hi ? d[3] : e1;
      b1v.x = hi ? e2   : d[4];  b1v.y = hi ? e3   : d[5];
      b1v.z = hi ? d[6] : e2;    b1v.w = hi ? d[7] : e3;
      // frag kt=2p+h, col-tile ct; lanes write consecutive 16B -> conflict-free
      *(u4*)(&Us[(size_t)(((2 * p + 0) * 4 + ct) * 64 + lane) * 8]) = b0v;
      *(u4*)(&Us[(size_t)(((2 * p + 1) * 4 + ct) * 64 + lane) * 8]) = b1v;
    }
  }

  __syncthreads();   // the only barrier: full U now resident in LDS

  // ================= stage 2: out = W^T @ U, row-block = wave =================
  floatx16 oacc[4];
#pragma unroll
  for (int cb = 0; cb < 4; ++cb)
#pragma unroll
    for (int i = 0; i < 16; ++i) oacc[cb][i] = 0.0f;

  short8 wA[2];
  short8 uB[2][4];
  wA[0] = *(const short8*)(Wf + (size_t)((wave * 16 + 0) * 64 + lane) * 8);
#pragma unroll
  for (int cb = 0; cb < 4; ++cb)
    uB[0][cb] = *(const short8*)(&Us[(size_t)((0 * 4 + cb) * 64 + lane) * 8]);

#pragma unroll
  for (int kt = 0; kt < 16; ++kt) {
    const int cur = kt & 1, nxt = cur ^ 1;
    if (kt < 15) {                       // distance-1 prefetch: A from L2, B from LDS
      wA[nxt] = *(const short8*)(Wf + (size_t)((wave * 16 + kt + 1) * 64 + lane) * 8);
#pragma unroll
      for (int cb = 0; cb < 4; ++cb)
        uB[nxt][cb] = *(const short8*)(&Us[(size_t)(((kt + 1) * 4 + cb) * 64 + lane) * 8]);
    }
#pragma unroll
    for (int cb = 0; cb < 4; ++cb)
      oacc[cb] = __builtin_amdgcn_mfma_f32_32x32x16_bf16(wA[cur], uB[cur][cb], oacc[cb], 0, 0, 0);
  }

  // ---- epilogue: D row=(r&3)+8*(r>>2)+4*hi, col=l31 ; wave owns rows 32w.. ----
  float* ob = out + (size_t)b * 16384 + (size_t)(32 * wave) * 128 + l31;
#pragma unroll
  for (int cb = 0; cb < 4; ++cb)
#pragma unroll
    for (int r = 0; r < 16; ++r) {
      int row = (r & 3) + 8 * (r >> 2) + 4 * hi;
      ob[row * 128 + 32 * cb] = oacc[cb][r];
    }
}

extern "C" void kernel_launch(void* const* d_in, const int* in_sizes, int n_in,
                              void* d_out, int out_size, void* d_ws, size_t ws_size,
                              hipStream_t stream) {
  const float* X = (const float*)d_in[0];      // [2048,256,256] f32
  const float* W = (const float*)d_in[1];      // [256,128] f32
  unsigned short* Wf = (unsigned short*)d_ws;  // 64 KB bf16 fragment buffer

  prep_w<<<16, 256, 0, stream>>>(W, Wf);
  spd_kernel<<<2048, 256, 0, stream>>>(X, Wf, (float*)d_out);
}